// Round 3
// baseline (87.495 us; speedup 1.0000x reference)
//
#include <hip/hip_runtime.h>

#define BB 4
#define NN 512
#define KK 512
#define DD 64
#define ROWS 8
// TAU = 4.0 -> softmax scale 0.25; b2 dropped (constant pre-softmax shift, softmax-invariant)

typedef float v2f __attribute__((ext_vector_type(2)));

// ws layout (floats): hq_ws [2048][64] (b1 folded) | hkT_ws [4][16][512][4] (hk transposed)

// ---------------- Kernel A: hq = Q@Wq + b1 (row-major), hk = K@Wk (transposed layout) ----
__global__ __launch_bounds__(256) void mlpattn_proj(const float* __restrict__ Q,
                                                    const float* __restrict__ Kp,
                                                    const float* __restrict__ W1,
                                                    const float* __restrict__ b1,
                                                    float* __restrict__ hq_ws,
                                                    float* __restrict__ hkT_ws) {
    const int lane = threadIdx.x & 63;
    const int wave = threadIdx.x >> 6;
    const int half = blockIdx.x >> 8;          // 0 = hq blocks, 1 = hk blocks
    const int blk  = blockIdx.x & 255;
    const int r0 = (blk * 4 + wave) * 2;       // rows 0..2046 step 2 (b*512 + n/k)
    if (half == 0) {
        const float* x0 = Q + (size_t)r0 * DD;
        const float* x1 = x0 + DD;
        float acc0 = 0.f, acc1 = 0.f;
#pragma unroll
        for (int d = 0; d < DD; ++d) {
            float w = W1[(2 * d) * DD + lane];     // coalesced, L1-hot
            acc0 = fmaf(x0[d], w, acc0);           // x: wave-uniform -> s_load
            acc1 = fmaf(x1[d], w, acc1);
        }
        float bb = b1[lane];
        hq_ws[(size_t)r0 * DD + lane] = acc0 + bb;
        hq_ws[(size_t)(r0 + 1) * DD + lane] = acc1 + bb;
    } else {
        const float* x0 = Kp + (size_t)r0 * DD;
        const float* x1 = x0 + DD;
        float acc0 = 0.f, acc1 = 0.f;
#pragma unroll
        for (int d = 0; d < DD; ++d) {
            float w = W1[(2 * d + 1) * DD + lane];
            acc0 = fmaf(x0[d], w, acc0);
            acc1 = fmaf(x1[d], w, acc1);
        }
        const int b = r0 >> 9;
        const int k = r0 & 511;
        const int j4 = lane >> 2, c = lane & 3;    // hkT[b][j4][k][c] = hk[k][4*j4+c]
        float* dst = hkT_ws + ((size_t)(b * 16 + j4) * KK) * 4 + c;
        dst[(size_t)k * 4] = acc0;
        dst[(size_t)(k + 1) * 4] = acc1;
    }
}

// ---------------- Kernel B: block = (b, 8 query rows), 512 threads, thread t <-> k=t ----
__global__ __launch_bounds__(512, 2) void mlpattn_main(const float* __restrict__ V,
                                                       const float* __restrict__ W2,
                                                       const float* __restrict__ hq_ws,
                                                       const float* __restrict__ hkT_ws,
                                                       float* __restrict__ out,
                                                       float* __restrict__ att_out) {
    __shared__ float s_att[ROWS * KK];           // 16 KB
    __shared__ float4 s_pv[32 * ROWS * 16];      // 64 KB (kg, r, dq)

    const int t = threadIdx.x;                   // = k for the res phase
    const int b  = blockIdx.x >> 6;              // 0..3
    const int ng = blockIdx.x & 63;              // row group
    const int row0 = ng * ROWS;

    // ---- res: hk[k][:] in 32 v2f VGPR pairs (coalesced loads), hq/W2 wave-uniform
    //      inner loop packed fp32: v_pk_add + v_max x2 + v_pk_fma -> 2 instr/element
    alignas(16) v2f hk2[32];
    {
        const float4* hkT4 = (const float4*)hkT_ws + (size_t)b * 16 * KK;
#pragma unroll
        for (int j4 = 0; j4 < 16; ++j4)
            ((float4*)hk2)[j4] = hkT4[(size_t)j4 * KK + t];   // lanes consecutive
    }
    const v2f* w2v = (const v2f*)W2;             // uniform -> SGPRs

    const float* hqb = hq_ws + ((size_t)b * NN + row0) * DD;
#pragma unroll
    for (int r = 0; r < ROWS; ++r) {
        const v2f* hq2 = (const v2f*)(hqb + r * DD);          // uniform -> SGPRs
        v2f a2 = {0.f, 0.f};
#pragma unroll
        for (int j2 = 0; j2 < 32; ++j2) {
            v2f tt = hq2[j2] + hk2[j2];                       // v_pk_add_f32
            tt = __builtin_elementwise_max(tt, (v2f)0.f);     // relu
            a2 += tt * w2v[j2];                               // v_pk_fma_f32
        }
        s_att[r * KK + t] = a2.x + a2.y;                      // stride-1: conflict-free
    }
    __syncthreads();

    // ---- softmax: wave per row, in-wave butterfly ----
    {
        const int lane = t & 63;
        const int w = t >> 6;                    // row 0..7
        float* sr = s_att + w * KK;
        float v[8];
        float mx = -1e30f;
#pragma unroll
        for (int i = 0; i < 8; ++i) { v[i] = sr[lane + 64 * i]; mx = fmaxf(mx, v[i]); }
#pragma unroll
        for (int off = 32; off; off >>= 1) mx = fmaxf(mx, __shfl_xor(mx, off, 64));
        float s = 0.f;
#pragma unroll
        for (int i = 0; i < 8; ++i) { v[i] = __expf((v[i] - mx) * 0.25f); s += v[i]; }
#pragma unroll
        for (int off = 32; off; off >>= 1) s += __shfl_xor(s, off, 64);
        float inv = 1.0f / s;
        float* ga = att_out + ((size_t)b * NN + row0 + w) * KK;
#pragma unroll
        for (int i = 0; i < 8; ++i) {
            float a = v[i] * inv;
            sr[lane + 64 * i] = a;
            ga[lane + 64 * i] = a;               // coalesced att output
        }
    }
    __syncthreads();

    // ---- PV: thread (dq, kg) accumulates 16 k for all 8 rows; V read once per block ----
    {
        const int dq = t & 15;
        const int kg = t >> 4;                   // 0..31
        const float4* V4 = (const float4*)V + (size_t)b * KK * 16;
        float4 a[ROWS];
#pragma unroll
        for (int r = 0; r < ROWS; ++r) a[r] = make_float4(0.f, 0.f, 0.f, 0.f);
#pragma unroll
        for (int kk = 0; kk < 16; ++kk) {
            const int k = kg * 16 + kk;
            float4 vv = V4[(size_t)k * 16 + dq]; // 4x256B segments per wave instr
#pragma unroll
            for (int r = 0; r < ROWS; ++r) {
                float p = s_att[r * KK + k];     // 4-addr broadcast, ~free
                a[r].x = fmaf(p, vv.x, a[r].x);
                a[r].y = fmaf(p, vv.y, a[r].y);
                a[r].z = fmaf(p, vv.z, a[r].z);
                a[r].w = fmaf(p, vv.w, a[r].w);
            }
        }
#pragma unroll
        for (int r = 0; r < ROWS; ++r)
            s_pv[(kg * ROWS + r) * 16 + dq] = a[r];   // even bank spread
    }
    __syncthreads();

    // ---- reduce 32 kg partials -> out ----
    float4* s_red = (float4*)s_att;              // s_att dead after PV barrier
    {
        const int o = t & 127;                   // r*16+dq
        const int g = t >> 7;                    // 0..3
        float4 s = make_float4(0.f, 0.f, 0.f, 0.f);
#pragma unroll
        for (int i = 0; i < 8; ++i) {
            float4 p = s_pv[(g * 8 + i) * 128 + o];
            s.x += p.x; s.y += p.y; s.z += p.z; s.w += p.w;
        }
        s_red[g * 128 + o] = s;
    }
    __syncthreads();
    if (t < 128) {
        float4 s0 = s_red[t], s1 = s_red[128 + t], s2 = s_red[256 + t], s3 = s_red[384 + t];
        float4 s = make_float4(s0.x + s1.x + s2.x + s3.x,
                               s0.y + s1.y + s2.y + s3.y,
                               s0.z + s1.z + s2.z + s3.z,
                               s0.w + s1.w + s2.w + s3.w);
        const int r = t >> 4, dq = t & 15;
        ((float4*)out)[((size_t)b * NN + row0 + r) * 16 + dq] = s;
    }
}

extern "C" void kernel_launch(void* const* d_in, const int* in_sizes, int n_in,
                              void* d_out, int out_size, void* d_ws, size_t ws_size,
                              hipStream_t stream) {
    const float* Q  = (const float*)d_in[0];
    const float* K  = (const float*)d_in[1];
    const float* V  = (const float*)d_in[2];
    const float* W1 = (const float*)d_in[3];
    const float* b1 = (const float*)d_in[4];
    const float* W2 = (const float*)d_in[5];
    // b2 (d_in[6]) unused: softmax-invariant constant shift

    float* out = (float*)d_out;                        // B*N*D
    float* att = (float*)d_out + BB * NN * DD;         // B*N*K
    float* hq_ws  = (float*)d_ws;                      // 512 KB
    float* hkT_ws = (float*)d_ws + BB * NN * DD;       // 512 KB

    mlpattn_proj<<<512, 256, 0, stream>>>(Q, K, W1, b1, hq_ws, hkT_ws);
    mlpattn_main<<<256, 512, 0, stream>>>(V, W2, hq_ws, hkT_ws, out, att);
}